// Round 1
// baseline (123.041 us; speedup 1.0000x reference)
//
#include <hip/hip_runtime.h>
#include <math.h>

#define NEGV (-1.0e9f)

__device__ __forceinline__ float clip1000(float v) {
  return fminf(fmaxf(v, -1000.0f), 1000.0f);
}

__launch_bounds__(256, 1)
__global__ void sim_kernel(const int* __restrict__ tables,
                           const int* __restrict__ sigma,
                           const int* __restrict__ x,
                           const int* __restrict__ base_obs,
                           const float* __restrict__ W1,
                           const float* __restrict__ b1,
                           const float* __restrict__ W2,
                           const float* __restrict__ b2,
                           const int* __restrict__ max_steps_p,
                           float* __restrict__ out,
                           int B, int V, int N)
{
  const int O = 64;
  const int HID = 128;
  const int b = blockIdx.x;
  const int tid = threadIdx.x;
  const int T = max_steps_p[0];

  __shared__ int s_idx[8192];
  __shared__ int s_idx2[8192];
  __shared__ int s_hist[32 * 64];
  __shared__ float s_feat[33][3];
  __shared__ float s_z[33];
  __shared__ int s_used[32];
  __shared__ int s_ycnt[32];
  __shared__ int s_nact, s_cnt, s_a, s_r, s_stopped;

  const int* tb = tables + (size_t)b * V * N;
  const int bo = base_obs[b];
  const int xb = x[b];

  if (tid < 32) s_used[tid] = 0;
  if (tid == 0) { s_nact = 0; s_stopped = 0; }
  __syncthreads();

  // Build initial active set: m0 = (tables[b,0,:] == base_obs[b])
  for (int n = tid; n < N; n += 256) {
    if (tb[n] == bo) { int p = atomicAdd(&s_nact, 1); s_idx[p] = n; }
  }
  __syncthreads();

  for (int t = 0; t < T; ++t) {
    if (s_stopped) {
      if (tid == 0) {
        out[b * T + t] = (float)V;           // action = V (stop)
        out[B * T + b * T + t] = 0.0f;       // response = 0
      }
      __syncthreads();
      continue;
    }
    const int nact = s_nact;

    // zero histograms
    for (int i = tid; i < 32 * O; i += 256) s_hist[i] = 0;
    __syncthreads();

    // counts[v][o] over active candidates
    const int npairs = nact * 32;
    for (int p = tid; p < npairs; p += 256) {
      int j = p >> 5, v = p & 31;
      int idx = s_idx[j];
      int lab = tb[(size_t)v * N + idx];
      atomicAdd(&s_hist[v * O + lab], 1);
    }
    __syncthreads();

    const float total = (float)(nact > 1 ? nact : 1);
    if (tid < 32) {
      long long sumsq = 0;
      for (int o = 0; o < O; ++o) {
        int c = s_hist[tid * O + o];
        sumsq += (long long)c * (long long)c;
      }
      float es = (float)sumsq / total;                    // exp_size[b,v]
      float steps = (tid == 0) ? 1000.0f : log2f(fmaxf(es, 1.0f));
      s_feat[tid][0] = clip1000(steps);
      s_feat[tid][1] = clip1000(es - 1.0f);
      s_feat[tid][2] = clip1000(es);
    } else if (tid == 32) {
      bool closed = (total <= 1.0f);
      s_feat[32][0] = clip1000(closed ? 0.0f : 1000.0f);
      s_feat[32][1] = clip1000(total - 1.0f);
      s_feat[32][2] = clip1000(total);
    }
    __syncthreads();

    // MLP: z[i] = gelu(feat @ W1 + b1) @ W2 + b2 ; 4 lanes per view
    if (tid < 132) {
      const int view = tid >> 2, l = tid & 3;
      const float f0 = s_feat[view][0], f1 = s_feat[view][1], f2 = s_feat[view][2];
      float zpart = 0.0f;
      {
        #pragma clang fp contract(off)
        for (int k = l * 32; k < l * 32 + 32; ++k) {
          float pre = f0 * W1[k] + f1 * W1[HID + k] + f2 * W1[2 * HID + k] + b1[k];
          float e = erff(pre / (float)M_SQRT2);
          float hg = 0.5f * pre * (1.0f + e);   // exact GELU
          zpart = zpart + hg * W2[k];
        }
      }
      zpart += __shfl_xor(zpart, 1);
      zpart += __shfl_xor(zpart, 2);
      if (l == 0) s_z[view] = zpart + b2[0];
    }
    __syncthreads();

    // action selection (literal replication of reference argmax chain)
    if (tid == 0) {
      int jstar = 0; float best = s_z[0];
      for (int i = 1; i < 33; ++i) {
        float v = s_z[i];
        if (v > best) { best = v; jstar = i; }   // strict > : first-max, like np.argmax
      }
      int a = 0; float bv = -3.0e9f;
      for (int i = 0; i < 33; ++i) {
        float val = (i == jstar) ? 1.0f : 0.0f;  // one-hot z
        if (i == 0) val = NEGV;                  // forbid view 0
        else if (i < 32 && s_used[i]) val = NEGV; // mask used
        if (val > bv) { bv = val; a = i; }
      }
      int r = 0;
      if (a == 32) {
        s_stopped = 1;                           // is_stop; used[31] update is inert
      } else {
        s_used[a] = 1;
        r = tb[(size_t)a * N + xb];
      }
      s_a = a; s_r = r;
      out[b * T + t] = (float)a;
      out[B * T + b * T + t] = (float)r;
    }
    __syncthreads();

    const int a = s_a, r = s_r;
    if (a != 32) {
      // filter: keep candidates whose label under view a equals r
      if (tid == 0) s_cnt = 0;
      __syncthreads();
      for (int j = tid; j < nact; j += 256) {
        int idx = s_idx[j];
        if (tb[(size_t)a * N + idx] == r) {
          int p = atomicAdd(&s_cnt, 1);
          s_idx2[p] = idx;
        }
      }
      __syncthreads();
      const int nc = s_cnt;
      for (int j = tid; j < nc; j += 256) s_idx[j] = s_idx2[j];
      if (tid == 0) s_nact = nc;
      __syncthreads();
    }
  }

  // y_logits: histogram sigma over surviving candidates
  if (tid < 32) s_ycnt[tid] = 0;
  __syncthreads();
  const int nfin = s_nact;
  const int* sg = sigma + (size_t)b * N;
  for (int j = tid; j < nfin; j += 256) {
    atomicAdd(&s_ycnt[sg[s_idx[j]]], 1);
  }
  __syncthreads();
  if (tid < 32) {
    float denom = (float)(nfin > 1 ? nfin : 1);
    float q = 1.0f / denom;                 // float32, matches w/denom per element
    int c = s_ycnt[tid];
    float p = 0.0f;
    for (int k = 0; k < c; ++k) p = p + q;  // sequential fl-adds == scatter-add of equal values
    out[2 * B * T + b * 32 + tid] = logf(fmaxf(p, 1e-9f));
  }
}

extern "C" void kernel_launch(void* const* d_in, const int* in_sizes, int n_in,
                              void* d_out, int out_size, void* d_ws, size_t ws_size,
                              hipStream_t stream) {
  const int* tables   = (const int*)d_in[0];
  const int* sigma    = (const int*)d_in[1];
  const int* x        = (const int*)d_in[2];
  const int* base_obs = (const int*)d_in[3];
  const float* W1 = (const float*)d_in[4];
  const float* b1 = (const float*)d_in[5];
  const float* W2 = (const float*)d_in[6];
  const float* b2 = (const float*)d_in[7];
  const int* msteps = (const int*)d_in[8];
  float* out = (float*)d_out;

  const int B = in_sizes[2];
  const int N = in_sizes[1] / B;
  const int V = in_sizes[0] / (B * N);

  sim_kernel<<<dim3(B), dim3(256), 0, stream>>>(
      tables, sigma, x, base_obs, W1, b1, W2, b2, msteps, out, B, V, N);
}

// Round 2
// 68.151 us; speedup vs baseline: 1.8054x; 1.8054x over previous
//
#include <hip/hip_runtime.h>
#include <math.h>

#define NEGV (-1.0e9f)

__device__ __forceinline__ float clip1000(float v) {
  return fminf(fmaxf(v, -1000.0f), 1000.0f);
}

__launch_bounds__(1024, 1)
__global__ void sim_kernel(const int* __restrict__ tables,
                           const int* __restrict__ sigma,
                           const int* __restrict__ x,
                           const int* __restrict__ base_obs,
                           const float* __restrict__ W1,
                           const float* __restrict__ b1,
                           const float* __restrict__ W2,
                           const float* __restrict__ b2,
                           const int* __restrict__ max_steps_p,
                           float* __restrict__ out,
                           int B, int V, int N)
{
  const int O = 64;
  const int b = blockIdx.x;
  const int tid = threadIdx.x;
  const int T = max_steps_p[0];

  __shared__ int s_idx[2][8192];          // candidate index lists (ping-pong)
  __shared__ int s_hist[32 * 64];
  __shared__ float s_feat[33][3];
  __shared__ float s_z[33];
  __shared__ int s_used[32];
  __shared__ int s_ycnt[32];
  __shared__ int s_resp[32];              // prefetched tables[b, v, x[b]]
  __shared__ float s_w1a[128], s_w1b[128], s_w1c[128], s_b1[128], s_w2[128];
  __shared__ float s_b2;
  __shared__ int s_nact, s_cnt, s_a, s_r;

  const int* tb = tables + (size_t)b * V * N;
  const int bo = base_obs[b];
  const int xb = x[b];

  // Stage MLP weights into LDS; prefetch per-view responses; init state.
  if (tid < 128) s_w1a[tid] = W1[tid];
  else if (tid < 256) s_w1b[tid - 128] = W1[tid];
  else if (tid < 384) s_w1c[tid - 256] = W1[tid];
  else if (tid < 512) s_b1[tid - 384] = b1[tid - 384];
  else if (tid < 640) s_w2[tid - 512] = W2[tid - 512];
  else if (tid == 640) s_b2 = b2[0];
  else if (tid >= 704 && tid < 736) s_resp[tid - 704] = tb[(size_t)(tid - 704) * N + xb];
  if (tid < 32) s_used[tid] = 0;
  if (tid == 0) s_nact = 0;
  __syncthreads();

  // Initial active set: m0 = (tables[b,0,:] == base_obs[b]); int4 coalesced scan.
  {
    const int4* tb4 = (const int4*)tb;
    for (int q = tid; q < (N >> 2); q += 1024) {
      int4 v4 = tb4[q];
      int base = q << 2;
      if (v4.x == bo) { int p = atomicAdd(&s_nact, 1); s_idx[0][p] = base; }
      if (v4.y == bo) { int p = atomicAdd(&s_nact, 1); s_idx[0][p] = base + 1; }
      if (v4.z == bo) { int p = atomicAdd(&s_nact, 1); s_idx[0][p] = base + 2; }
      if (v4.w == bo) { int p = atomicAdd(&s_nact, 1); s_idx[0][p] = base + 3; }
    }
  }
  __syncthreads();

  int cur = 0;
  int t = 0;
  for (; t < T; ++t) {
    const int nact = s_nact;

    // zero histograms
    for (int i = tid; i < 32 * O; i += 1024) s_hist[i] = 0;
    __syncthreads();

    // counts[v][o]: view v = tid>>5, 32 lanes per view, 4 loads batched
    {
      const int v = tid >> 5, g = tid & 31;
      const int* row = tb + (size_t)v * N;
      int* hv = s_hist + v * O;
      for (int base0 = 0; base0 < nact; base0 += 128) {
        int lab[4]; int valid = 0;
        #pragma unroll
        for (int u = 0; u < 4; ++u) {
          int j = base0 + u * 32 + g;
          if (j < nact) { lab[u] = row[s_idx[cur][j]]; valid |= (1 << u); }
        }
        #pragma unroll
        for (int u = 0; u < 4; ++u)
          if (valid & (1 << u)) atomicAdd(&hv[lab[u]], 1);
      }
    }
    __syncthreads();

    // features
    const float total = (float)(nact > 1 ? nact : 1);
    if (tid < 32) {
      long long sumsq = 0;
      for (int o = 0; o < O; ++o) {
        int c = s_hist[tid * O + o];
        sumsq += (long long)c * (long long)c;
      }
      float es = (float)sumsq / total;                    // exp_size[b,v]
      float steps = (tid == 0) ? 1000.0f : log2f(fmaxf(es, 1.0f));
      s_feat[tid][0] = clip1000(steps);
      s_feat[tid][1] = clip1000(es - 1.0f);
      s_feat[tid][2] = clip1000(es);
    } else if (tid == 32) {
      bool closed = (total <= 1.0f);
      s_feat[32][0] = clip1000(closed ? 0.0f : 1000.0f);
      s_feat[32][1] = clip1000(total - 1.0f);
      s_feat[32][2] = clip1000(total);
    }
    __syncthreads();

    // MLP: 16 lanes per view, 8 hidden units each, identical partition per view
    if (tid < 528) {
      const int view = tid >> 4, l = tid & 15;
      const float f0 = s_feat[view][0], f1 = s_feat[view][1], f2 = s_feat[view][2];
      float zp = 0.0f;
      {
        #pragma clang fp contract(off)
        for (int k = l * 8; k < l * 8 + 8; ++k) {
          float pre = f0 * s_w1a[k] + f1 * s_w1b[k] + f2 * s_w1c[k] + s_b1[k];
          float e = erff(pre / (float)M_SQRT2);
          float hg = 0.5f * pre * (1.0f + e);   // exact GELU
          zp = zp + hg * s_w2[k];
        }
      }
      zp += __shfl_xor(zp, 1);
      zp += __shfl_xor(zp, 2);
      zp += __shfl_xor(zp, 4);
      zp += __shfl_xor(zp, 8);
      if (l == 0) s_z[view] = zp + s_b2;
    }
    __syncthreads();

    // action selection (literal replication of reference argmax chain)
    if (tid == 0) {
      int jstar = 0; float best = s_z[0];
      for (int i = 1; i < 33; ++i) {
        float v2 = s_z[i];
        if (v2 > best) { best = v2; jstar = i; }  // strict > : first-max, like np.argmax
      }
      int a = 0; float bv = -3.0e9f;
      for (int i = 0; i < 33; ++i) {
        float val = (i == jstar) ? 1.0f : 0.0f;   // one-hot z
        if (i == 0) val = NEGV;                   // forbid view 0
        else if (i < 32 && s_used[i]) val = NEGV; // mask already-used views
        if (val > bv) { bv = val; a = i; }
      }
      int r = 0;
      if (a != 32) { s_used[a] = 1; r = s_resp[a]; }
      s_a = a; s_r = r;
      out[b * T + t] = (float)a;
      out[B * T + b * T + t] = (float)r;
    }
    __syncthreads();

    const int a = s_a, r = s_r;
    if (a == 32) break;   // stopped; remaining steps handled after loop

    // filter into the other buffer (ping-pong, no copy-back)
    if (tid == 0) s_cnt = 0;
    __syncthreads();
    {
      const int* rowa = tb + (size_t)a * N;
      for (int j = tid; j < nact; j += 1024) {
        int idx = s_idx[cur][j];
        if (rowa[idx] == r) { int p = atomicAdd(&s_cnt, 1); s_idx[cur ^ 1][p] = idx; }
      }
    }
    __syncthreads();
    if (tid == 0) s_nact = s_cnt;
    cur ^= 1;
    __syncthreads();
  }

  // stopped early: remaining actions are V (stop), responses 0
  if (t < T && tid == 0) {
    for (int tt = t + 1; tt < T; ++tt) {
      out[b * T + tt] = (float)V;
      out[B * T + b * T + tt] = 0.0f;
    }
  }

  // y_logits: histogram sigma over surviving candidates
  if (tid < 32) s_ycnt[tid] = 0;
  __syncthreads();
  const int nfin = s_nact;
  const int* sg = sigma + (size_t)b * N;
  for (int j = tid; j < nfin; j += 1024) {
    atomicAdd(&s_ycnt[sg[s_idx[cur][j]]], 1);
  }
  __syncthreads();
  if (tid < 32) {
    float denom = (float)(nfin > 1 ? nfin : 1);
    float q = 1.0f / denom;                 // float32, matches w/denom per element
    int c = s_ycnt[tid];
    float p = 0.0f;
    for (int k = 0; k < c; ++k) p = p + q;  // sequential fl-adds == scatter-add of equal values
    out[2 * B * T + b * 32 + tid] = logf(fmaxf(p, 1e-9f));
  }
}

extern "C" void kernel_launch(void* const* d_in, const int* in_sizes, int n_in,
                              void* d_out, int out_size, void* d_ws, size_t ws_size,
                              hipStream_t stream) {
  const int* tables   = (const int*)d_in[0];
  const int* sigma    = (const int*)d_in[1];
  const int* x        = (const int*)d_in[2];
  const int* base_obs = (const int*)d_in[3];
  const float* W1 = (const float*)d_in[4];
  const float* b1 = (const float*)d_in[5];
  const float* W2 = (const float*)d_in[6];
  const float* b2 = (const float*)d_in[7];
  const int* msteps = (const int*)d_in[8];
  float* out = (float*)d_out;

  const int B = in_sizes[2];
  const int N = in_sizes[1] / B;
  const int V = in_sizes[0] / (B * N);

  sim_kernel<<<dim3(B), dim3(1024), 0, stream>>>(
      tables, sigma, x, base_obs, W1, b1, W2, b2, msteps, out, B, V, N);
}